// Round 8
// baseline (181.939 us; speedup 1.0000x reference)
//
#include <hip/hip_runtime.h>
#include <cstdint>
#include <cstddef>

typedef __bf16 bf16x8 __attribute__((ext_vector_type(8)));
typedef float  f32x16 __attribute__((ext_vector_type(16)));
typedef int    i32x4  __attribute__((ext_vector_type(4)));

#define QMAX 7.0f
#define SCALE_MIN 2e-16f

#define BAR()     asm volatile("s_barrier" ::: "memory")
#define WAITVM(N) asm volatile("s_waitcnt vmcnt(" #N ")" ::: "memory")

// ---------------------------------------------------------------------------
// Kernel 1: per-output-channel fake-quant of w [256,256,3,3] -> bf16 wq[tap][o][c]
// ---------------------------------------------------------------------------
__global__ __launch_bounds__(256) void quant_w_kernel(const float* __restrict__ w,
                                                      __bf16* __restrict__ wq) {
    const int o = blockIdx.x;
    const int t = threadIdx.x;
    const float* wo = w + (size_t)o * 2304;

    float vals[9];
    float m = 0.f;
    #pragma unroll
    for (int i = 0; i < 9; ++i) {
        float v = wo[t + i * 256];
        vals[i] = v;
        m = fmaxf(m, fabsf(v));
    }
    #pragma unroll
    for (int off = 32; off >= 1; off >>= 1) m = fmaxf(m, __shfl_down(m, off));
    __shared__ float red[4];
    __shared__ float s_scale;
    if ((t & 63) == 0) red[t >> 6] = m;
    __syncthreads();
    if (t == 0) {
        float am = fmaxf(fmaxf(red[0], red[1]), fmaxf(red[2], red[3]));
        s_scale = fmaxf(am / QMAX, SCALE_MIN);
    }
    __syncthreads();
    const float scale = s_scale;

    #pragma unroll
    for (int i = 0; i < 9; ++i) {
        int idx = t + i * 256;           // = c*9 + tap
        int c = idx / 9;
        int tap = idx - c * 9;
        float q = rintf(vals[i] / scale);          // round-half-even, matches jnp.round
        q = fminf(QMAX, fmaxf(-QMAX, q));
        wq[(size_t)tap * 65536 + (size_t)o * 256 + c] = (__bf16)(q * scale);
    }
}

// ---------------------------------------------------------------------------
// Kernel 2: x NCHW fp32 [32,256,56,56] -> padded NHWC bf16 [32][58][58][256]
// ---------------------------------------------------------------------------
__global__ __launch_bounds__(256) void convert_x_kernel(const float* __restrict__ x,
                                                        __bf16* __restrict__ xpad) {
    __shared__ float tile[32][33];
    const int n  = blockIdx.z;
    const int c0 = blockIdx.y * 32;
    const int p0 = blockIdx.x * 32;
    const int tx = threadIdx.x & 31;
    const int ty = threadIdx.x >> 5;

    #pragma unroll
    for (int r = 0; r < 4; ++r) {
        int c = c0 + ty + r * 8;
        tile[ty + r * 8][tx] = x[((size_t)(n * 256 + c)) * 3136 + p0 + tx];
    }
    __syncthreads();
    #pragma unroll
    for (int r = 0; r < 4; ++r) {
        int p = p0 + ty + r * 8;
        int h = p / 56, wcol = p - h * 56;
        xpad[(((size_t)n * 58 + h + 1) * 58 + (wcol + 1)) * 256 + c0 + tx] =
            (__bf16)tile[tx][ty + r * 8];
    }
}

// ---------------------------------------------------------------------------
// Kernel 2b: zero the 1-cell halo of xpad.
// ---------------------------------------------------------------------------
__global__ __launch_bounds__(256) void zero_halo_kernel(__bf16* __restrict__ xpad) {
    const int t = blockIdx.x * 256 + threadIdx.x;
    const int cvec = t & 31;
    const int r    = t >> 5;
    const int n    = r / 228;
    const int pos  = r - n * 228;
    if (n >= 32) return;
    int h, wcol;
    if      (pos < 58)  { h = 0;          wcol = pos; }
    else if (pos < 116) { h = 57;         wcol = pos - 58; }
    else if (pos < 172) { h = pos - 115;  wcol = 0; }
    else                { h = pos - 171;  wcol = 57; }
    i32x4* dst = (i32x4*)(xpad + (((size_t)n * 58 + h) * 58 + wcol) * 256);
    dst[cvec] = (i32x4){0, 0, 0, 0};
}

// ---------------------------------------------------------------------------
// Kernel 3: implicit-GEMM conv.
// Block 256o x 128pos, 256 thr (4 waves 2Mx2N), per-wave 128x64 as 4x2 frags
// of mfma_f32_32x32x16_bf16 (16 MFMA + 12 ds_read_b128 per BK=32 step;
// 32x32 shape = 17% cheaper MFMA pipe than 16x16 at same LDS bytes).
// 72 K-steps. TRIPLE-buffered LDS (3 x 24KB = 72KB) -> 2 blocks/CU.
// TWO-step lookahead: iter s = { WAITVM(6) [s-loads issued 2 iters ago]
//   -> BAR -> STAGE(s+2) into buf[(s+2)%3] [race-free: post-BAR, all waves
//   done reading buf[s-1] = buf[s+2]] -> 12 ds_read -> 16 MFMA }.
// Counted vmcnt only; ONE barrier per step; ~2 step-times of load latency
// tolerance.
// Swizzle: stored chunk16 = logical ^ ((row>>2)&3) on 64B rows. Each 16-lane
// quarter of a fragment ds_read_b128 covers ALL 32 banks at exactly 2-way
// (2-way is free, m136); fixes R7's quarter-granularity conflicts (1.08e7).
// Staging source pre-swizzled (tid&3)^((tid>>4)&3); gload_lds dest linear.
// Grid 784 = 8*98 XCD-bijective.
// ---------------------------------------------------------------------------
__device__ __forceinline__ void gload_lds16(const void* g, void* l) {
    __builtin_amdgcn_global_load_lds((const __attribute__((address_space(1))) void*)g,
                                     (__attribute__((address_space(3))) void*)l,
                                     16, 0, 0);
}

__global__ __launch_bounds__(256, 2) void conv_mfma_kernel(const __bf16* __restrict__ xpad,
                                                           const __bf16* __restrict__ wq,
                                                           float* __restrict__ out) {
    extern __shared__ __align__(16) char lds[];   // 73728 B = 3 x (A 16K + B 8K)
    const int tid  = threadIdx.x;
    const int wv   = tid >> 6;          // 0..3
    const int lane = tid & 63;
    const int bid  = blockIdx.x;
    const int swz  = (bid & 7) * 98 + (bid >> 3);    // 784 = 8*98 bijection
    const int p0   = swz * 128;

    const int wm = wv >> 1;        // 0..1 : o 128-half
    const int wn = wv & 1;         // 0..1 : pos 64-half

    // ---- staging setup: 6 issues/step of 4 KB (64 rows x 64 B) -----------
    const int trow   = tid >> 2;                     // 0..63 row within issue
    const int schunk = (tid & 3) ^ ((tid >> 4) & 3); // pre-swizzled src chunk
    // A-issue j (0..3): o row = j*64 + trow
    const __bf16* pA[4];
    #pragma unroll
    for (int j = 0; j < 4; ++j)
        pA[j] = wq + (size_t)(j * 64 + trow) * 256 + schunk * 8;
    // B-issue j (0..1): pos = p0 + j*64 + trow
    const __bf16* pBs[2];
    #pragma unroll
    for (int j = 0; j < 2; ++j) {
        int pos = p0 + j * 64 + trow;                // < 100352 (exact tiling)
        int ni = pos / 3136;
        int hw = pos - ni * 3136;
        int h = hw / 56, w = hw - h * 56;
        pBs[j] = xpad + (((size_t)ni * 58 + h) * 58 + w) * 256 + schunk * 8;
    }
    // wave-uniform LDS dest bases (HW adds lane*16):
    const int adst = wv * 1024;            // + j*4096   (A region: 16 KB)
    const int bdst = 16384 + wv * 1024;    // + j*4096   (B region: 8 KB)

    // ---- fragment read offsets (64B rows; stored chunk = c ^ ((row>>2)&3))
    const int l31 = lane & 31;
    const int lk  = lane >> 5;                       // k-half within 32B
    const int rsw = (lane >> 2) & 3;                 // (row>>2)&3 for all frags
    int kx[2];
    #pragma unroll
    for (int ks = 0; ks < 2; ++ks)
        kx[ks] = ((ks * 2 + lk) ^ rsw) * 16;
    int arow[4], brow[2];
    #pragma unroll
    for (int m = 0; m < 4; ++m) arow[m] = (wm * 128 + m * 32 + l31) * 64;
    #pragma unroll
    for (int n = 0; n < 2; ++n) brow[n] = 16384 + (wn * 64 + n * 32 + l31) * 64;

    f32x16 acc[4][2];
    #pragma unroll
    for (int m = 0; m < 4; ++m)
        #pragma unroll
        for (int n = 0; n < 2; ++n)
            acc[m][n] = (f32x16)(0.f);

    // ---- stage helper: 6 gloads (A0..A3, B0, B1) = 6 vmcnt entries -------
    #define STAGE(STEP, BUF)                                                  \
        {                                                                     \
            const int tap_ = (STEP) >> 3, cc_ = (STEP) & 7;                   \
            const int kh_ = tap_ / 3, kw_ = tap_ - kh_ * 3;                   \
            const size_t aoff_ = (size_t)tap_ * 65536 + cc_ * 32;             \
            const size_t boff_ = (size_t)(kh_ * 58 + kw_) * 256 + cc_ * 32;   \
            gload_lds16(pA[0] + aoff_, (BUF) + adst);                         \
            gload_lds16(pA[1] + aoff_, (BUF) + adst + 4096);                  \
            gload_lds16(pA[2] + aoff_, (BUF) + adst + 8192);                  \
            gload_lds16(pA[3] + aoff_, (BUF) + adst + 12288);                 \
            gload_lds16(pBs[0] + boff_, (BUF) + bdst);                        \
            gload_lds16(pBs[1] + boff_, (BUF) + bdst + 4096);                 \
        }

    // ---- prologue: steps 0,1 into buf0,buf1 ------------------------------
    STAGE(0, lds);
    STAGE(1, lds + 24576);

    int co = 0;                                      // (s%3)*24576
    #pragma unroll 1
    for (int s = 0; s < 72; ++s) {
        if (s < 71) { WAITVM(6); } else { WAITVM(0); }
        BAR();
        int so = co + 49152; if (so >= 73728) so -= 73728;   // (s+2)%3 buffer
        if (s < 70) STAGE(s + 2, lds + so);

        const char* B = lds + co;
        bf16x8 a[4][2], b[2][2];
        #pragma unroll
        for (int m = 0; m < 4; ++m)
            #pragma unroll
            for (int ks = 0; ks < 2; ++ks)
                a[m][ks] = *(const bf16x8*)(B + arow[m] + kx[ks]);
        #pragma unroll
        for (int n = 0; n < 2; ++n)
            #pragma unroll
            for (int ks = 0; ks < 2; ++ks)
                b[n][ks] = *(const bf16x8*)(B + brow[n] + kx[ks]);

        __builtin_amdgcn_s_setprio(1);
        #pragma unroll
        for (int ks = 0; ks < 2; ++ks)
            #pragma unroll
            for (int m = 0; m < 4; ++m)
                #pragma unroll
                for (int n = 0; n < 2; ++n)
                    acc[m][n] = __builtin_amdgcn_mfma_f32_32x32x16_bf16(
                        a[m][ks], b[n][ks], acc[m][n], 0, 0, 0);
        __builtin_amdgcn_s_setprio(0);

        co += 24576; if (co == 73728) co = 0;
    }
    #undef STAGE

    // ---- epilogue: 32x32 C/D: col(pos)=lane&31, row(o)=(r&3)+8*(r>>2)+4*hi
    const int hi = lane >> 5;
    #pragma unroll
    for (int n = 0; n < 2; ++n) {
        const int pos = p0 + wn * 64 + n * 32 + l31;
        const int ni = pos / 3136;
        const int hw = pos - ni * 3136;
        float* ob = out + (size_t)ni * 802816 + hw;
        #pragma unroll
        for (int m = 0; m < 4; ++m) {
            const int om = wm * 128 + m * 32 + 4 * hi;
            #pragma unroll
            for (int r = 0; r < 16; ++r) {
                const int o = om + (r & 3) + 8 * (r >> 2);
                ob[(size_t)o * 3136] = acc[m][n][r];
            }
        }
    }
}

// ---------------------------------------------------------------------------
// Fallback: naive direct conv (only if ws_size too small).
// ---------------------------------------------------------------------------
__global__ __launch_bounds__(256) void conv_naive_kernel(const float* __restrict__ x,
                                                         const float* __restrict__ w,
                                                         float* __restrict__ out) {
    const int n = blockIdx.z;
    const int o = blockIdx.y;
    const int strip = blockIdx.x;
    __shared__ float wqs[2304];
    __shared__ float red[4];
    __shared__ float s_scale;
    const float* wo = w + (size_t)o * 2304;
    float m = 0.f;
    for (int i = threadIdx.x; i < 2304; i += 256) m = fmaxf(m, fabsf(wo[i]));
    #pragma unroll
    for (int off = 32; off >= 1; off >>= 1) m = fmaxf(m, __shfl_down(m, off));
    if ((threadIdx.x & 63) == 0) red[threadIdx.x >> 6] = m;
    __syncthreads();
    if (threadIdx.x == 0) {
        float am = fmaxf(fmaxf(red[0], red[1]), fmaxf(red[2], red[3]));
        s_scale = fmaxf(am / QMAX, SCALE_MIN);
    }
    __syncthreads();
    const float scale = s_scale;
    for (int i = threadIdx.x; i < 2304; i += 256) {
        float q = rintf(wo[i] / scale);
        q = fminf(QMAX, fmaxf(-QMAX, q));
        wqs[i] = q * scale;
    }
    __syncthreads();
    int p = strip * 256 + threadIdx.x;
    if (p >= 3136) return;
    int h = p / 56, wcol = p - h * 56;
    float acc = 0.f;
    for (int c = 0; c < 256; ++c) {
        const float* xc = x + ((size_t)(n * 256 + c)) * 3136;
        const float* wk = wqs + c * 9;
        #pragma unroll
        for (int kh = 0; kh < 3; ++kh) {
            int hh = h + kh - 1;
            if (hh < 0 || hh > 55) continue;
            #pragma unroll
            for (int kw = 0; kw < 3; ++kw) {
                int ww2 = wcol + kw - 1;
                if (ww2 < 0 || ww2 > 55) continue;
                acc += xc[hh * 56 + ww2] * wk[kh * 3 + kw];
            }
        }
    }
    out[((size_t)(n * 256 + o)) * 3136 + p] = acc;
}

// ---------------------------------------------------------------------------
extern "C" void kernel_launch(void* const* d_in, const int* in_sizes, int n_in,
                              void* d_out, int out_size, void* d_ws, size_t ws_size,
                              hipStream_t stream) {
    const float* x = (const float*)d_in[0];
    const float* w = (const float*)d_in[1];
    float* out = (float*)d_out;

    const size_t WQ_BYTES   = 9ull * 256 * 256 * 2;            // 1,179,648
    const size_t XPAD_OFF   = WQ_BYTES;
    const size_t XPAD_BYTES = 32ull * 58 * 58 * 256 * 2;       // 55,083,008

    if (ws_size >= XPAD_OFF + XPAD_BYTES) {
        __bf16* wq   = (__bf16*)d_ws;
        __bf16* xpad = (__bf16*)((char*)d_ws + XPAD_OFF);
        hipFuncSetAttribute((const void*)conv_mfma_kernel,
                            hipFuncAttributeMaxDynamicSharedMemorySize, 73728);
        zero_halo_kernel<<<912, 256, 0, stream>>>(xpad);
        quant_w_kernel<<<256, 256, 0, stream>>>(w, wq);
        convert_x_kernel<<<dim3(98, 8, 32), 256, 0, stream>>>(x, xpad);
        conv_mfma_kernel<<<784, 256, 73728, stream>>>(xpad, wq, out);
    } else {
        conv_naive_kernel<<<dim3(13, 256, 32), 256, 0, stream>>>(x, w, out);
    }
}